// Round 12
// baseline (127.451 us; speedup 1.0000x reference)
//
#include <hip/hip_runtime.h>
#include <hip/hip_bf16.h>

// Problem: B=4, L=2048, D_MODEL=1024, H=16, D_QKV=64.
// Reference einsum 'bhlk,blhd->blhd' contracts k over logits only; softmax sums to 1,
// so attention output == v and the net reduces to:
//   out = x @ Wc + fc_b,  Wc[m][j] = sum_{hd} w_v[h][m][d] * fc_w[j][hd]
// Two launches:
//   prep: blocks 0-255 fold Wc^T || blocks 256-1023 cast x->bf16.
//   final_gemm: 128x128, BK=128, 512 blocks, 2/CU, chunked XCD swizzle.
// History: R0 prep rewrite 151->133.5. R10 128x128 intensity 131.1. R11 fold dist-2
//   prefetch + fgemm chunked swizzle 127.2 (best). Calibrated budget: fills ~87
//   (harness-fixed) + prep ~16 + fgemm ~22 + gaps ~2.
// Round-12 (two orthogonal continuations):
//   (a) fold XCD-local mapping: default gave each XCD 6MB working set (>4MB L2) ->
//       128MB L3 traffic ~ L3 BW over 8us. New: XCD k owns j-tiles {2k,2k+1} x all m
//       (bijective) -> 512KB fcw + 4MB wv per XCD, L3 traffic ~36MB. Mapping-only.
//   (b) fgemm BK=128: barrier-drain events 16->8, same 2-barrier structure, same
//       k-ascending accumulation (k0 step 128, slabs s=0..3 ascending) -> bit-identical.
//       LDS 64KB x 2 blocks/CU = 128KB <= 160 -> occupancy UNCHANGED (dodges m132's
//       BK=128 occupancy trap). Each wave stages its own slab: 8 A + 8 B chunks.

typedef __attribute__((ext_vector_type(8))) short bf16x8;
typedef __attribute__((ext_vector_type(4))) float f32x4;

__device__ __forceinline__ f32x4 mfma16(bf16x8 a, bf16x8 b, f32x4 c) {
  return __builtin_amdgcn_mfma_f32_16x16x32_bf16(a, b, c, 0, 0, 0);
}

// fp32 -> bf16 bits, round-to-nearest-even
__device__ __forceinline__ unsigned short f2b(float f) {
  unsigned int u = __builtin_bit_cast(unsigned int, f);
  return (unsigned short)((u + 0x7fffu + ((u >> 16) & 1u)) >> 16);
}

__device__ __forceinline__ bf16x8 cvt8(float4 a, float4 b) {
  bf16x8 r;
  r[0] = (short)f2b(a.x); r[1] = (short)f2b(a.y); r[2] = (short)f2b(a.z); r[3] = (short)f2b(a.w);
  r[4] = (short)f2b(b.x); r[5] = (short)f2b(b.y); r[6] = (short)f2b(b.z); r[7] = (short)f2b(b.w);
  return r;
}

// async global->LDS, 16 B per lane (m97 pattern; LDS dest = wave-uniform base + lane*16)
__device__ __forceinline__ void gld_lds16(const void* g, void* l) {
  __builtin_amdgcn_global_load_lds((const __attribute__((address_space(1))) unsigned int*)g,
                                   (__attribute__((address_space(3))) unsigned int*)l, 16, 0, 0);
}

// prep: blocks 0-255 fold Wc^T; blocks 256-1023 cast x->bf16. No inter-block dependency.
__global__ __launch_bounds__(256) void prep(const float* __restrict__ x,
                                            const float* __restrict__ wv,
                                            const float* __restrict__ fcw,
                                            unsigned short* __restrict__ xb,
                                            unsigned short* __restrict__ wcT) {
  // Fold LDS: per-h 64x64 bf16 slabs of A=fcw[j][k] and B=wv-as-[m][d], double-buffered.
  // 32 KB total. XOR swizzle (row&7)<<4 on the in-row byte so the stride-128B fragment
  // reads are <=2-way bank aliases (free) instead of 16-way.
  __shared__ __align__(16) short As[2][64 * 64];
  __shared__ __align__(16) short Bs[2][64 * 64];

  int bid = blockIdx.x, t = threadIdx.x;
  int wid = t >> 6, lane = t & 63, l16 = lane & 15, quad = lane >> 4;

  if (bid < 256) {
    // wcT[j][m] = sum_{h,d} fcw[j][h*64+d] * wv[h][m][d]; 64x64 output tile, 4 waves 2x2.
    // XCD-local mapping (XCD = bid%8 round-robin): XCD k owns j-tiles {2k,2k+1} x all m.
    int xcd = bid & 7, idx = bid >> 3;
    int j0 = (xcd * 2 + (idx & 1)) * 64;   // j tile
    int m0 = (idx >> 1) * 64;              // m tile
    int wr = wid >> 1, wc = wid & 1;
    int rowt = t >> 3, colb = (t & 7) * 8;  // staging: chunk c row = c*32+rowt, 8 floats at colb

    f32x4 acc[2][2];
#pragma unroll
    for (int a = 0; a < 2; a++)
#pragma unroll
      for (int b = 0; b < 2; b++) acc[a][b] = (f32x4){0.f, 0.f, 0.f, 0.f};

    // two in-flight h-slab register sets (distance-2 prefetch; static names per rule #20)
    float4 ra0[2][2], rb0[2][2], ra1[2][2], rb1[2][2];

#define LOADH(h, ra, rb)                                                             \
    {                                                                                \
      _Pragma("unroll")                                                              \
      for (int c = 0; c < 2; c++) {                                                  \
        int row = c * 32 + rowt;                                                     \
        const float* pa = fcw + (j0 + row) * 1024 + (h) * 64 + colb;                 \
        ra[c][0] = *reinterpret_cast<const float4*>(pa);                             \
        ra[c][1] = *reinterpret_cast<const float4*>(pa + 4);                         \
        const float* pb = wv + (h) * 65536 + (m0 + row) * 64 + colb;                 \
        rb[c][0] = *reinterpret_cast<const float4*>(pb);                             \
        rb[c][1] = *reinterpret_cast<const float4*>(pb + 4);                         \
      }                                                                              \
    }
#define STOREH(buf, ra, rb)                                                          \
    {                                                                                \
      _Pragma("unroll")                                                              \
      for (int c = 0; c < 2; c++) {                                                  \
        int row = c * 32 + rowt;                                                     \
        int bo = row * 128 + ((colb * 2) ^ ((row & 7) << 4));                        \
        *reinterpret_cast<bf16x8*>((char*)As[buf] + bo) = cvt8(ra[c][0], ra[c][1]);  \
        *reinterpret_cast<bf16x8*>((char*)Bs[buf] + bo) = cvt8(rb[c][0], rb[c][1]);  \
      }                                                                              \
    }
#define COMPUTE_FOLD(buf)                                                            \
    {                                                                                \
      bf16x8 af[2][2], bg[2][2];                                                     \
      _Pragma("unroll")                                                              \
      for (int rt = 0; rt < 2; rt++) {                                               \
        int rowf = wr * 32 + rt * 16 + l16;                                          \
        int rbase = rowf * 128, rx = (rowf & 7) << 4;                                \
        af[rt][0] = *reinterpret_cast<const bf16x8*>((char*)As[buf] + rbase + ((quad * 16) ^ rx));        \
        af[rt][1] = *reinterpret_cast<const bf16x8*>((char*)As[buf] + rbase + ((64 + quad * 16) ^ rx));   \
      }                                                                              \
      _Pragma("unroll")                                                              \
      for (int ct = 0; ct < 2; ct++) {                                               \
        int rowf = wc * 32 + ct * 16 + l16;                                          \
        int rbase = rowf * 128, rx = (rowf & 7) << 4;                                \
        bg[ct][0] = *reinterpret_cast<const bf16x8*>((char*)Bs[buf] + rbase + ((quad * 16) ^ rx));        \
        bg[ct][1] = *reinterpret_cast<const bf16x8*>((char*)Bs[buf] + rbase + ((64 + quad * 16) ^ rx));   \
      }                                                                              \
      _Pragma("unroll")                                                              \
      for (int ks = 0; ks < 2; ks++)                                                 \
        _Pragma("unroll")                                                            \
        for (int rt = 0; rt < 2; rt++)                                               \
          _Pragma("unroll")                                                          \
          for (int ct = 0; ct < 2; ct++)                                             \
            acc[rt][ct] = mfma16(af[rt][ks], bg[ct][ks], acc[rt][ct]);               \
    }

    // prologue: h0 and h1 both in flight; h0 staged to buf0
    LOADH(0, ra0, rb0);
    LOADH(1, ra1, rb1);
    STOREH(0, ra0, rb0);
    __syncthreads();

    // unrolled x2: iter h=hh (buf0) then h=hh+1 (buf1). Same h/ks-ascending MFMA
    // chain as before -> bit-identical. LOADH(h+2) issued ~1.5 iters before its STOREH.
    for (int hh = 0; hh < 16; hh += 2) {
      if (hh < 14) LOADH(hh + 2, ra0, rb0);
      COMPUTE_FOLD(0);
      STOREH(1, ra1, rb1);            // h = hh+1 data -> buf1 (hh+1 <= 15 always)
      __syncthreads();

      if (hh < 13) LOADH(hh + 3, ra1, rb1);
      COMPUTE_FOLD(1);
      if (hh < 14) STOREH(0, ra0, rb0);  // h = hh+2 data -> buf0
      __syncthreads();
    }
#undef LOADH
#undef STOREH
#undef COMPUTE_FOLD

#pragma unroll
    for (int rt = 0; rt < 2; rt++)
#pragma unroll
      for (int ct = 0; ct < 2; ct++) {
        int jj = j0 + wr * 32 + rt * 16 + quad * 4;
        int mm = m0 + wc * 32 + ct * 16 + l16;
#pragma unroll
        for (int r = 0; r < 4; r++) wcT[(jj + r) * 1024 + mm] = f2b(acc[rt][ct][r]);
      }
  } else {
    // cast: x fp32 -> bf16. 8.4M elems = 4096 chunks of 2048; 768 blocks grid-stride
    // (~5.3 chunks each) so HBM latency is hidden by TLP (4 blocks/CU overall grid).
    int cb = bid - 256;
    for (int ch = cb; ch < 4096; ch += 768) {
      int idx = ch * 2048 + t * 8;
      float4 a = *reinterpret_cast<const float4*>(x + idx);
      float4 b = *reinterpret_cast<const float4*>(x + idx + 4);
      *reinterpret_cast<bf16x8*>(xb + idx) = cvt8(a, b);
    }
  }
}

// out[i][j] = sum_m xb[i][m]*wcT[j][m] + fcb[j].  M=8192,N=1024,K=1024.
// 128x128 tile, BK=128 (four 32-k slabs), 8 K-steps, 512 blocks, 4 waves each owning
// a 64x64 sub-tile (4x4 frags), 64 KB LDS, 2-barrier K-step, 2 blocks/CU (128KB LDS/CU).
// Chunked bijective swizzle (512 = 8 XCD x 64): XCD owns 8 M x 8 N consecutive tiles
// -> per-XCD L2 working set 2MB A + 2MB B (fits 4MB).
__global__ __launch_bounds__(256, 2) void final_gemm(const unsigned short* __restrict__ xb,
                                                     const unsigned short* __restrict__ wcT,
                                                     const float* __restrict__ fcb,
                                                     float* __restrict__ out) {
  __shared__ __align__(16) unsigned short As[4 * 128 * 32];  // 32 KB  [slab][row][32]
  __shared__ __align__(16) unsigned short Bs[4 * 128 * 32];  // 32 KB
  int t = threadIdx.x, wid = t >> 6, lane = t & 63, l16 = lane & 15, quad = lane >> 4;
  int wr = wid >> 1, wc = wid & 1;
  int swz = (blockIdx.x & 7) * 64 + (blockIdx.x >> 3);  // bijective: 512 = 8 x 64
  int row0 = (swz >> 3) * 128;   // M tile (64)
  int col0 = (swz & 7) * 128;    // N tile (8) — fastest within an XCD chunk

  // Staging: 32 x 1KB chunks each for A and B; chunk blk = wid*8+j (wave wid owns slab
  // s = blk>>3 = wid): rows (blk&7)*16 + lane>>2, k-quarter lane&3. LDS linear chunk
  // layout blk*1KB + lane*16B == [slab][row][32] addressing (verified arithmetic).
  int w8 = wid * 8;
  const unsigned short* Ap[8];
  const unsigned short* Bp[8];
#pragma unroll
  for (int j = 0; j < 8; j++) {
    int blk = w8 + j, s = blk >> 3;
    int row = (blk & 7) * 16 + (lane >> 2), kq = lane & 3;
    Ap[j] = xb + (row0 + row) * 1024 + s * 32 + kq * 8;
    Bp[j] = wcT + (col0 + row) * 1024 + s * 32 + kq * 8;
  }

  f32x4 acc[4][4];
#pragma unroll
  for (int rt = 0; rt < 4; rt++)
#pragma unroll
    for (int ct = 0; ct < 4; ct++) acc[rt][ct] = (f32x4){0.f, 0.f, 0.f, 0.f};

  for (int k0 = 0; k0 < 1024; k0 += 128) {
    __syncthreads();
#pragma unroll
    for (int j = 0; j < 8; j++) {
      gld_lds16(Ap[j] + k0, &As[(w8 + j) * 512 + lane * 8]);
      gld_lds16(Bp[j] + k0, &Bs[(w8 + j) * 512 + lane * 8]);
    }
    __syncthreads();
#pragma unroll
    for (int s = 0; s < 4; s++) {   // slabs ascending: same k order as BK=64 version
      bf16x8 af[4], bfr[4];
#pragma unroll
      for (int rt = 0; rt < 4; rt++)
        af[rt] = *reinterpret_cast<const bf16x8*>(&As[s * 4096 + (wr * 64 + rt * 16 + l16) * 32 + quad * 8]);
#pragma unroll
      for (int ct = 0; ct < 4; ct++)
        bfr[ct] = *reinterpret_cast<const bf16x8*>(&Bs[s * 4096 + (wc * 64 + ct * 16 + l16) * 32 + quad * 8]);
#pragma unroll
      for (int rt = 0; rt < 4; rt++)
#pragma unroll
        for (int ct = 0; ct < 4; ct++)
          acc[rt][ct] = mfma16(af[rt], bfr[ct], acc[rt][ct]);
    }
  }

#pragma unroll
  for (int ct = 0; ct < 4; ct++) {
    int j = col0 + wc * 64 + ct * 16 + l16;
    float bias = fcb[j];
#pragma unroll
    for (int rt = 0; rt < 4; rt++) {
      int i0 = row0 + wr * 64 + rt * 16 + quad * 4;
      f32x4 a = acc[rt][ct];
#pragma unroll
      for (int r = 0; r < 4; r++) out[(i0 + r) * 1024 + j] = a[r] + bias;
    }
  }
}

extern "C" void kernel_launch(void* const* d_in, const int* in_sizes, int n_in,
                              void* d_out, int out_size, void* d_ws, size_t ws_size,
                              hipStream_t stream) {
  const float* x   = (const float*)d_in[0];
  // d_in[1] mask, d_in[2] w_q, d_in[3] w_k: dead per reference semantics
  const float* wv  = (const float*)d_in[4];
  const float* fcw = (const float*)d_in[5];
  const float* fcb = (const float*)d_in[6];
  float* out = (float*)d_out;

  char* ws = (char*)d_ws;
  unsigned short* xb  = (unsigned short*)(ws);              // 16 MB (8192x1024 bf16)
  unsigned short* wcT = (unsigned short*)(ws + 16777216);   // 2 MB  (1024x1024 bf16)

  prep<<<1024, 256, 0, stream>>>(x, wv, fcw, xb, wcT);
  final_gemm<<<512, 256, 0, stream>>>(xb, wcT, fcb, out);
}